// Round 9
// baseline (189.982 us; speedup 1.0000x reference)
//
#include <hip/hip_runtime.h>
#include <hip/hip_bf16.h>
#include <math.h>

#define B_SZ 512
#define D_SZ 2048
#define M_SZ 128
#define H_SZ 128
#define BCHUNK 32
#define NCHUNKS (B_SZ / BCHUNK)

typedef __attribute__((ext_vector_type(8))) short bf16x8;
typedef __attribute__((ext_vector_type(4))) float f32x4;
typedef __attribute__((ext_vector_type(4))) unsigned short us4;

__device__ __forceinline__ unsigned short f2bf(float f) {
    unsigned u = __builtin_bit_cast(unsigned, f);
    u += 0x7fffu + ((u >> 16) & 1u);   // round-to-nearest-even
    return (unsigned short)(u >> 16);
}

// tanh-form gelu: h * sigmoid(1.59577 h + 0.0713548 h^3).
__device__ __forceinline__ float gelu_fast(float h) {
    float u = h * h;
    float z = h * fmaf(0.0713548162726f, u, 1.5957691216057308f);
    float e = __expf(-z);
    return __fdividef(h, 1.0f + e);
}

// lgkm-only barrier: leaves global/DMA traffic in flight (T4); rule-18 fencing.
__device__ __forceinline__ void lds_barrier() {
    __builtin_amdgcn_sched_barrier(0);
    asm volatile("s_waitcnt lgkmcnt(0)" ::: "memory");
    __builtin_amdgcn_sched_barrier(0);
    __builtin_amdgcn_s_barrier();
    __builtin_amdgcn_sched_barrier(0);
}

__device__ __forceinline__ void wait_vm4() {
    __builtin_amdgcn_sched_barrier(0);
    asm volatile("s_waitcnt vmcnt(4)" ::: "memory");
    __builtin_amdgcn_sched_barrier(0);
}
__device__ __forceinline__ void wait_vm0() {
    __builtin_amdgcn_sched_barrier(0);
    asm volatile("s_waitcnt vmcnt(0)" ::: "memory");
    __builtin_amdgcn_sched_barrier(0);
}

__global__ __launch_bounds__(256, 2) void nlm_kernel(
    const float* __restrict__ x,   // [B, D, M]
    const float* __restrict__ W1,  // [D, H, M]
    const float* __restrict__ b1,  // [D, H]
    const float* __restrict__ W2,  // [D, H]
    const float* __restrict__ b2,  // [D]
    float* __restrict__ out)       // [B, D]
{
    // W1s: bf16, 256-B rows, XOR-swizzled (byte ^= (row&7)<<4).
    // Xs:  fp32 double-buffer, 512-B rows, granule-XOR swizzle via
    //      pre-swizzled DMA SOURCE (rule #21: linear dest + inv-swz source
    //      + swz read — same involution on both sides).
    __shared__ __align__(16) unsigned short W1s[H_SZ * M_SZ];      // 32 KB
    __shared__ __align__(16) float Xs[2][BCHUNK * M_SZ];           // 2x16 KB
    __shared__ float red[2][BCHUNK];
    __shared__ float outLDS[B_SZ];                                 // 2 KB

    const int bid = blockIdx.x;
    const int d = (bid & 7) * 256 + (bid >> 3);   // XCD-aware d swizzle

    const int tid  = threadIdx.x;
    const int l    = tid & 63;
    const int w    = tid >> 6;     // 4 waves: 2 (B) x 2 (H)
    const int wr   = w >> 1;       // 0..1 -> 16 B-rows each
    const int wc   = w & 1;        // 0..1 -> 64 H each
    const int lrow = l & 15;
    const int lk   = l >> 4;
    const int swz16 = (lrow & 7) << 4;

    // ---- stage W1[d] -> LDS bf16 (fully coalesced) ----
    const float* W1d = W1 + (size_t)d * (H_SZ * M_SZ);
    #pragma unroll
    for (int i = 0; i < 16; ++i) {
        int idx = tid + i * 256;          // float4 index 0..4095
        int r = idx >> 5, c4 = idx & 31;
        const float4 v = *(const float4*)(W1d + (r << 7) + (c4 << 2));
        us4 u; u.x = f2bf(v.x); u.y = f2bf(v.y); u.z = f2bf(v.z); u.w = f2bf(v.w);
        int byte = (r << 8) + ((c4 << 3) ^ ((r & 7) << 4));
        *(us4*)((char*)W1s + byte) = u;
    }

    // ---- per-lane epilogue constants ----
    float w2r[4], b1r[4];
    #pragma unroll
    for (int n = 0; n < 4; ++n) {
        int hh = wc * 64 + n * 16 + lrow;
        w2r[n] = W2[(size_t)d * H_SZ + hh];
        b1r[n] = b1[(size_t)d * H_SZ + hh];
    }
    const float b2v = b2[d];

    // ---- drain all prior vmem so DMA vmcnt counting is exact ----
    wait_vm0();

    // ---- DMA stage: chunk c -> Xs[buf]. Each wave stages 8 rows via 4
    // width-16 gload_lds. Dest is wave-uniform + lane*16 (linear); source
    // is granule-XOR pre-swizzled within each 512-B row. ----
    const char* xb = (const char*)x;
    auto stage = [&](int c, int buf) {
        #pragma unroll
        for (int j = 0; j < 4; ++j) {
            int rl  = w * 8 + j * 2 + (l >> 5);            // local row 0..31
            int col = ((l & 31) << 4) ^ ((rl & 7) << 4);   // swizzled byte col
            const void* src = xb + ((size_t)(c * BCHUNK + rl) * D_SZ + d) * (M_SZ * 4) + col;
            void* dst = (char*)&Xs[buf][0] + (size_t)(w * 8 + j * 2) * 512;
            __builtin_amdgcn_global_load_lds(
                (const __attribute__((address_space(1))) void*)src,
                (__attribute__((address_space(3))) void*)dst, 16, 0, 0);
        }
    };

    stage(0, 0);
    stage(1, 1);

    for (int c = 0; c < NCHUNKS; ++c) {
        // my DMA(c) done (4 younger = DMA(c+1) still in flight), then block-wide
        if (c == NCHUNKS - 1) wait_vm0(); else wait_vm4();
        lds_barrier();   // barrier A: buf[c&1] staged by all waves; W1s ready (c==0)

        const char* xbuf = (const char*)&Xs[c & 1][0];

        // ---- MFMA: 16 B-rows x 64 H per wave, K = M = 128 ----
        f32x4 acc[4];
        #pragma unroll
        for (int n = 0; n < 4; ++n) acc[n] = (f32x4){0.f, 0.f, 0.f, 0.f};

        #pragma unroll
        for (int k = 0; k < 4; ++k) {
            const int R  = wr * 16 + lrow;
            const int sw = (R & 7) << 4;
            const int cb = (k << 7) + (lk << 5);           // byte col (fp32 row)
            const char* base = xbuf + (R << 9);
            f32x4 x0 = *(const f32x4*)(base + (cb ^ sw));
            f32x4 x1 = *(const f32x4*)(base + ((cb + 16) ^ sw));
            bf16x8 af;
            af[0] = (short)f2bf(x0[0]); af[1] = (short)f2bf(x0[1]);
            af[2] = (short)f2bf(x0[2]); af[3] = (short)f2bf(x0[3]);
            af[4] = (short)f2bf(x1[0]); af[5] = (short)f2bf(x1[1]);
            af[6] = (short)f2bf(x1[2]); af[7] = (short)f2bf(x1[3]);
            const int wcol = ((k << 6) | (lk << 4)) ^ swz16;
            #pragma unroll
            for (int n = 0; n < 4; ++n) {
                int rowW = wc * 64 + n * 16 + lrow;
                bf16x8 bb = *(const bf16x8*)((const char*)W1s + (rowW << 8) + wcol);
                acc[n] = __builtin_amdgcn_mfma_f32_16x16x32_bf16(af, bb, acc[n], 0, 0, 0);
            }
        }

        // ---- epilogue: +b1, gelu, dot W2, 16-lane reduce ----
        // C/D: col(H) = wc*64 + n*16 + (lane&15), row(B) = wr*16 + lk*4 + r
        float p[4] = {0.f, 0.f, 0.f, 0.f};
        #pragma unroll
        for (int n = 0; n < 4; ++n) {
            const float w2v = w2r[n];
            const float b1v = b1r[n];
            #pragma unroll
            for (int r = 0; r < 4; ++r)
                p[r] += gelu_fast(acc[n][r] + b1v) * w2v;
        }
        #pragma unroll
        for (int off = 1; off < 16; off <<= 1)
            #pragma unroll
            for (int r = 0; r < 4; ++r)
                p[r] += __shfl_xor(p[r], off, 64);

        if (lrow == 0) {
            #pragma unroll
            for (int r = 0; r < 4; ++r)
                red[wc][wr * 16 + lk * 4 + r] = p[r];
        }

        lds_barrier();   // barrier B: all reads of buf[c&1] done + red visible

        // buf[c&1] is now free: issue DMA for chunk c+2 (stays in flight
        // across the next chunk's barriers — counted, never drained)
        if (c + 2 < NCHUNKS) stage(c + 2, c & 1);

        if (tid < BCHUNK)
            outLDS[c * BCHUNK + tid] = red[0][tid] + red[1][tid] + b2v;
    }

    // ---- final store burst (only global stores in the kernel) ----
    lds_barrier();
    out[(size_t)tid * D_SZ + d]         = outLDS[tid];
    out[(size_t)(tid + 256) * D_SZ + d] = outLDS[tid + 256];
}

extern "C" void kernel_launch(void* const* d_in, const int* in_sizes, int n_in,
                              void* d_out, int out_size, void* d_ws, size_t ws_size,
                              hipStream_t stream) {
    const float* x  = (const float*)d_in[0];
    const float* W1 = (const float*)d_in[1];
    const float* b1 = (const float*)d_in[2];
    const float* W2 = (const float*)d_in[3];
    const float* b2 = (const float*)d_in[4];
    float* out = (float*)d_out;

    hipLaunchKernelGGL(nlm_kernel, dim3(D_SZ), dim3(256), 0, stream,
                       x, W1, b1, W2, b2, out);
}

// Round 10
// 159.724 us; speedup vs baseline: 1.1894x; 1.1894x over previous
//
#include <hip/hip_runtime.h>
#include <hip/hip_bf16.h>
#include <math.h>

#define B_SZ 512
#define D_SZ 2048
#define M_SZ 128
#define H_SZ 128
#define BCHUNK 32
#define NCHUNKS (B_SZ / BCHUNK)

typedef __attribute__((ext_vector_type(8))) short bf16x8;
typedef __attribute__((ext_vector_type(4))) float f32x4;
typedef __attribute__((ext_vector_type(4))) unsigned short us4;

__device__ __forceinline__ unsigned short f2bf(float f) {
    unsigned u = __builtin_bit_cast(unsigned, f);
    u += 0x7fffu + ((u >> 16) & 1u);   // round-to-nearest-even
    return (unsigned short)(u >> 16);
}

// tanh-form gelu: h * sigmoid(1.59577 h + 0.0713548 h^3).
// |err vs exact erf-gelu| <= ~3.5e-4 (peak near |h|~2); our |h| <~ 1.4.
__device__ __forceinline__ float gelu_fast(float h) {
    float u = h * h;
    float z = h * fmaf(0.0713548162726f, u, 1.5957691216057308f);
    float e = __expf(-z);
    return __fdividef(h, 1.0f + e);
}

// lgkm-only barrier: global loads/stores stay in flight across it (T4);
// rule-18 sched_barrier fencing. Verified correct in rounds 6/8.
__device__ __forceinline__ void lds_barrier() {
    __builtin_amdgcn_sched_barrier(0);
    asm volatile("s_waitcnt lgkmcnt(0)" ::: "memory");
    __builtin_amdgcn_sched_barrier(0);
    __builtin_amdgcn_s_barrier();
    __builtin_amdgcn_sched_barrier(0);
}

__global__ __launch_bounds__(256, 4) void nlm_kernel(
    const float* __restrict__ x,   // [B, D, M]
    const float* __restrict__ W1,  // [D, H, M]
    const float* __restrict__ b1,  // [D, H]
    const float* __restrict__ W2,  // [D, H]
    const float* __restrict__ b2,  // [D]
    float* __restrict__ out)       // [B, D]
{
    // 32 KB LDS total -> with VGPR<=128 this gives 4 blocks/CU (16 waves).
    // Phase 1: whole buffer stages W1 (bf16, XOR-swizzled rows).
    // Phase 2 (after W1 frags pulled to registers): same buffer holds
    //          Xs [32][128] bf16 (8 KB) + red [4][32] (0.5 KB).
    __shared__ __align__(16) unsigned char smem[32 * 1024];
    unsigned short* W1tmp = (unsigned short*)smem;          // [H][M] staging
    unsigned short* Xs    = (unsigned short*)smem;          // [BCHUNK][M]
    float*          red   = (float*)(smem + 8192);          // [4][BCHUNK]

    const int bid = blockIdx.x;
    const int d = (bid & 7) * 256 + (bid >> 3);   // XCD-aware d swizzle

    const int tid   = threadIdx.x;
    const int l     = tid & 63;
    const int w     = tid >> 6;     // 4 waves; wave w owns H [w*32, w*32+32)
    const int lrow  = l & 15;
    const int lk    = l >> 4;
    const int swz16 = (lrow & 7) << 4;

    // ---- T14 issue-early: chunk-0 X loads first (in flight during W1 setup).
    // 32 lanes per row -> each row is a 512-B contiguous read.
    const int xr_row = tid >> 5;          // 0..7
    const int xr_c4  = tid & 31;          // float4 column
    float4 xr[4];
    #pragma unroll
    for (int i = 0; i < 4; ++i)
        xr[i] = *(const float4*)(x + ((size_t)(xr_row + i * 8) * D_SZ + d) * M_SZ + (xr_c4 << 2));

    // ---- stage W1[d] -> LDS bf16 (64 KB contiguous, fully coalesced),
    // rows XOR-swizzled: byte ^= (row&7)<<4 (G4/T2) ----
    const float* W1d = W1 + (size_t)d * (H_SZ * M_SZ);
    #pragma unroll
    for (int i = 0; i < 16; ++i) {
        int idx = tid + i * 256;          // float4 index 0..4095
        int r = idx >> 5, c4 = idx & 31;
        const float4 v = *(const float4*)(W1d + (r << 7) + (c4 << 2));
        us4 u; u.x = f2bf(v.x); u.y = f2bf(v.y); u.z = f2bf(v.z); u.w = f2bf(v.w);
        int byte = (r << 8) + ((c4 << 3) ^ ((r & 7) << 4));
        *(us4*)((char*)W1tmp + byte) = u;
    }

    // ---- per-lane epilogue constants (H = w*32 + n*16 + lrow) ----
    float w2r[2], b1r[2];
    #pragma unroll
    for (int n = 0; n < 2; ++n) {
        int hh = w * 32 + n * 16 + lrow;
        w2r[n] = W2[(size_t)d * H_SZ + hh];
        b1r[n] = b1[(size_t)d * H_SZ + hh];
    }
    const float b2v = b2[d];

    lds_barrier();   // W1tmp fully staged

    // ---- pull this wave's W1 B-fragments into registers (32 VGPR) ----
    bf16x8 w1f[2][4];
    #pragma unroll
    for (int n = 0; n < 2; ++n)
        #pragma unroll
        for (int k = 0; k < 4; ++k) {
            int rowW = w * 32 + n * 16 + lrow;
            int colb = ((k << 6) | (lk << 4)) ^ swz16;
            w1f[n][k] = *(const bf16x8*)((const char*)W1tmp + (rowW << 8) + colb);
        }

    lds_barrier();   // frag reads done -> smem reusable as Xs/red

    for (int c = 0; c < NCHUNKS; ++c) {
        // ---- consume staged regs: convert + write Xs ----
        #pragma unroll
        for (int i = 0; i < 4; ++i) {
            int r = xr_row + i * 8;       // local row 0..31
            us4 u; u.x = f2bf(xr[i].x); u.y = f2bf(xr[i].y);
                   u.z = f2bf(xr[i].z); u.w = f2bf(xr[i].w);
            int byte = (r << 8) + ((xr_c4 << 3) ^ ((r & 7) << 4));
            *(us4*)((char*)Xs + byte) = u;
        }
        lds_barrier();   // bar1: Xs visible to all waves

        // ---- issue next chunk's X loads; in flight across MFMA+epilogue ----
        if (c + 1 < NCHUNKS) {
            const size_t b0n = (size_t)(c + 1) * BCHUNK;
            #pragma unroll
            for (int i = 0; i < 4; ++i)
                xr[i] = *(const float4*)(x + ((b0n + xr_row + i * 8) * D_SZ + d) * M_SZ + (xr_c4 << 2));
        }

        // ---- MFMA: 32 B-rows x this wave's 32 H, K = M = 128.
        // Only A-frags come from LDS (8 ds_read_b128); B is in registers. ----
        f32x4 acc[2][2];
        #pragma unroll
        for (int m = 0; m < 2; ++m)
            #pragma unroll
            for (int n = 0; n < 2; ++n)
                acc[m][n] = (f32x4){0.f, 0.f, 0.f, 0.f};

        #pragma unroll
        for (int k = 0; k < 4; ++k) {
            const int colb = ((k << 6) | (lk << 4)) ^ swz16;
            bf16x8 a0 = *(const bf16x8*)((const char*)Xs + ((0 * 16 + lrow) << 8) + colb);
            bf16x8 a1 = *(const bf16x8*)((const char*)Xs + ((1 * 16 + lrow) << 8) + colb);
            acc[0][0] = __builtin_amdgcn_mfma_f32_16x16x32_bf16(a0, w1f[0][k], acc[0][0], 0, 0, 0);
            acc[0][1] = __builtin_amdgcn_mfma_f32_16x16x32_bf16(a0, w1f[1][k], acc[0][1], 0, 0, 0);
            acc[1][0] = __builtin_amdgcn_mfma_f32_16x16x32_bf16(a1, w1f[0][k], acc[1][0], 0, 0, 0);
            acc[1][1] = __builtin_amdgcn_mfma_f32_16x16x32_bf16(a1, w1f[1][k], acc[1][1], 0, 0, 0);
        }

        // ---- epilogue: +b1, fast gelu, dot W2, 16-lane reduce (32 H/wave) ----
        // C/D: col(H) = w*32 + n*16 + (lane&15), row(B) = m*16 + lk*4 + r  [m89]
        float p[2][4];
        #pragma unroll
        for (int m = 0; m < 2; ++m)
            #pragma unroll
            for (int r = 0; r < 4; ++r)
                p[m][r] = 0.f;

        #pragma unroll
        for (int n = 0; n < 2; ++n) {
            const float w2v = w2r[n];
            const float b1v = b1r[n];
            #pragma unroll
            for (int m = 0; m < 2; ++m)
                #pragma unroll
                for (int r = 0; r < 4; ++r)
                    p[m][r] += gelu_fast(acc[m][n][r] + b1v) * w2v;
        }

        #pragma unroll
        for (int off = 1; off < 16; off <<= 1)
            #pragma unroll
            for (int m = 0; m < 2; ++m)
                #pragma unroll
                for (int r = 0; r < 4; ++r)
                    p[m][r] += __shfl_xor(p[m][r], off, 64);

        if (lrow == 0) {
            #pragma unroll
            for (int m = 0; m < 2; ++m)
                #pragma unroll
                for (int r = 0; r < 4; ++r)
                    red[w * BCHUNK + m * 16 + lk * 4 + r] = p[m][r];
        }
        lds_barrier();   // bar2: red visible; all Xs reads retired

        if (tid < BCHUNK) {
            float v = red[tid] + red[BCHUNK + tid] + red[2 * BCHUNK + tid]
                    + red[3 * BCHUNK + tid] + b2v;
            out[(size_t)(c * BCHUNK + tid) * D_SZ + d] = v;   // L2-absorbed scatter
        }
    }
}

extern "C" void kernel_launch(void* const* d_in, const int* in_sizes, int n_in,
                              void* d_out, int out_size, void* d_ws, size_t ws_size,
                              hipStream_t stream) {
    const float* x  = (const float*)d_in[0];
    const float* W1 = (const float*)d_in[1];
    const float* b1 = (const float*)d_in[2];
    const float* W2 = (const float*)d_in[3];
    const float* b2 = (const float*)d_in[4];
    float* out = (float*)d_out;

    hipLaunchKernelGGL(nlm_kernel, dim3(D_SZ), dim3(256), 0, stream,
                       x, W1, b1, W2, b2, out);
}